// Round 8
// baseline (512.694 us; speedup 1.0000x reference)
//
#include <hip/hip_runtime.h>

typedef unsigned short u16;
typedef __attribute__((ext_vector_type(8))) __bf16 bf16x8;
typedef __attribute__((ext_vector_type(8))) unsigned short ushort8;
typedef __attribute__((ext_vector_type(4))) unsigned short ushort4v;
typedef __attribute__((ext_vector_type(4))) float floatx4;

__device__ __forceinline__ float b2f(u16 u) {
  union { unsigned int i; float f; } v; v.i = ((unsigned int)u) << 16; return v.f;
}
__device__ __forceinline__ u16 f2b(float f) {
  union { float f; unsigned int i; } v; v.f = f;
  unsigned int u = v.i;
  unsigned int r = (u + 0x7fffu + ((u >> 16) & 1u)) >> 16;
  return (u16)r;
}
__device__ __forceinline__ float fast_tanh(float z) {
  float e = __expf(2.0f * z);
  return 1.0f - 2.0f / (e + 1.0f);
}
__device__ __forceinline__ float gelu_f(float x) {
  float t = fast_tanh(0.7978845608028654f * (x + 0.044715f * x * x * x));
  return 0.5f * x * (1.0f + t);
}
__device__ __forceinline__ floatx4 mfma16(bf16x8 a, bf16x8 b, floatx4 c) {
  return __builtin_amdgcn_mfma_f32_16x16x32_bf16(a, b, c, 0, 0, 0);
}
#define GLL16(gp, lp)                                                        \
  __builtin_amdgcn_global_load_lds(                                          \
      (const __attribute__((address_space(1))) unsigned int*)(gp),           \
      (__attribute__((address_space(3))) unsigned int*)(lp), 16, 0, 0)

// ---------- dtype detector: fp32 inputs (flag=1) vs bf16 (flag=0) ---------------
__global__ __launch_bounds__(256) void detect_dtype(
    const u16* __restrict__ x, int* __restrict__ flag) {
  __shared__ int cnt;
  if (threadIdx.x == 0) cnt = 0;
  __syncthreads();
  int ok = 0;
  #pragma unroll
  for (int k = 0; k < 16; ++k) {
    int idx = threadIdx.x + k * 256;
    u16 u = x[2 * idx];
    int e = (u >> 7) & 0xff;
    ok += (e >= 110 && e <= 143) ? 1 : 0;
  }
  atomicAdd(&cnt, ok);
  __syncthreads();
  if (threadIdx.x == 0) *flag = (cnt < 2048) ? 1 : 0;
}

// ---------- ONE prep kernel: 6 weight transposes + bias convert + x convert -----
struct WPtrs { const void* in[6]; };
struct BiasPtrs { const void* p[10]; };
__constant__ int kBiasOffs[11] = {0, 768, 1536, 2304, 3072, 6144,
                                  6912, 7680, 8448, 9216, 9984};
__global__ __launch_bounds__(256) void prep_all(
    WPtrs wp, BiasPtrs bp, const void* __restrict__ x,
    const int* __restrict__ flag, u16* __restrict__ WQKVT,
    u16* __restrict__ WOT, u16* __restrict__ W1T, u16* __restrict__ W2T,
    u16* __restrict__ BIAS, u16* __restrict__ XC) {
  const int id = blockIdx.x;
  const int tid = threadIdx.x;
  const int fp32 = *flag;
  if (id < 6912) {                       // weight transpose tiles
    __shared__ u16 tile[32][33];
    const void* in; u16* out; int K, N, bx, by;
    if (id < 2304) {                     // wq, wk, wv, wo : 768x768
      int widx = id / 576, r = id % 576;
      in = wp.in[widx];
      out = (widx < 3) ? (WQKVT + (size_t)widx * 768 * 768) : WOT;
      K = 768; N = 768; bx = r % 24; by = r / 24;
    } else if (id < 4608) {              // w1: 768x3072
      int r = id - 2304;
      in = wp.in[4]; out = W1T; K = 768; N = 3072; bx = r % 96; by = r / 96;
    } else {                             // w2: 3072x768
      int r = id - 4608;
      in = wp.in[5]; out = W2T; K = 3072; N = 768; bx = r % 24; by = r / 24;
    }
    const int tx = tid & 31, ty = tid >> 5;
    int xi = bx * 32 + tx;
    int y0 = by * 32;
    #pragma unroll
    for (int i = ty; i < 32; i += 8) {
      size_t src = (size_t)(y0 + i) * N + xi;
      tile[i][tx] = fp32 ? f2b(((const float*)in)[src]) : ((const u16*)in)[src];
    }
    __syncthreads();
    int xo = by * 32 + tx;
    int yo0 = bx * 32;
    #pragma unroll
    for (int i = ty; i < 32; i += 8)
      out[(size_t)(yo0 + i) * K + xo] = tile[tx][i];
  } else if (id < 6952) {                // biases + LN params (9984 elems)
    int t = (id - 6912) * 256 + tid;
    if (t < 9984) {
      int seg = 0;
      #pragma unroll
      for (int s = 0; s < 10; ++s) seg += (t >= kBiasOffs[s + 1]) ? 1 : 0;
      int j = t - kBiasOffs[seg];
      float v = fp32 ? ((const float*)bp.p[seg])[j]
                     : b2f(((const u16*)bp.p[seg])[j]);
      BIAS[t] = f2b(v);
    }
  } else {                               // x convert (1,572,864 x 4-elem groups)
    int i = (id - 6952) * 256 + tid;
    ushort4v o;
    if (fp32) {
      floatx4 v = ((const floatx4*)x)[i];
      #pragma unroll
      for (int j = 0; j < 4; ++j) o[j] = f2b(v[j]);
    } else {
      o = ((const ushort4v*)x)[i];
    }
    ((ushort4v*)XC)[i] = o;
  }
}

// ---------- GEMM: BK=32 DOUBLE-BUFFERED LDS, one barrier/iter -------------------
// Pipeline: issue(buf0); loop{ barrier; issue(next buf); compute(cur buf); }.
// The compiler's vmcnt(0)-before-barrier now drains loads that flew during a
// full compute phase (r7 structure exposed the whole load latency per iter:
// FFN1 @547TF, MfmaUtil 22%, 4.5x over both roofline floors).
// LDS segments are chunk-major 1KB (lane i -> row=i&15, kchunk=i>>4) so
// fragment ds_read_b128 is 2-way bank aliasing (free, m136) w/o padding.
// SWAPPED MFMA operands (C^T frags, vectorized stores), nt-outer (srcA reuse,
// r4/r5 A/B: cycling srcA costs ~35%).
// Modes: 0=std, 1=gelu, 2=QKV (cols>=voff scatter-transposed to VT).
template <int BN, int MODE>
__global__ __launch_bounds__(256) void gemm_bt(
    const u16* __restrict__ A, const u16* __restrict__ Bt,
    const u16* __restrict__ bias, u16* __restrict__ C,
    u16* __restrict__ VTp, int N, int K, int voff) {
  constexpr int BM = 128, BK = 32;
  constexpr int NT = BN / 32;
  constexpr int ASEG = BM / 16;          // 8 segs of 1 KB per buffer
  constexpr int BSEG = BN / 16;          // 8 (BN=128) or 4 (BN=64)
  __shared__ u16 As[2 * ASEG * 512];     // 16 KB
  __shared__ u16 Bs[2 * BSEG * 512];     // 16 or 8 KB
  const int tid = threadIdx.x;
  const int lane = tid & 63, wid = tid >> 6;
  const int wm = wid & 1, wn = wid >> 1;
  const int m0 = blockIdx.x * BM, n0 = blockIdx.y * BN;
  const int lr = lane & 15, lq = lane >> 4;
  const int srow = lane & 15;            // staging: row within seg
  const int schk = lane >> 4;            // staging: k-chunk (0..3)
  floatx4 acc[4][NT] = {};
  const int NIT = K / BK;

  auto issue = [&](int buf, int k0) {
    #pragma unroll
    for (int i = 0; i < 2; ++i) {        // A: 8 segs over 4 waves
      int seg = wid * 2 + i;
      const u16* gp = &A[(size_t)(m0 + seg * 16 + srow) * K + k0 + schk * 8];
      GLL16(gp, &As[buf * (ASEG * 512) + seg * 512]);
    }
    #pragma unroll
    for (int i = 0; i < BSEG / 4; ++i) { // B: BSEG segs over 4 waves
      int seg = wid * (BSEG / 4) + i;
      const u16* gp = &Bt[(size_t)(n0 + seg * 16 + srow) * K + k0 + schk * 8];
      GLL16(gp, &Bs[buf * (BSEG * 512) + seg * 512]);
    }
  };

  issue(0, 0);
  for (int it = 0; it < NIT; ++it) {
    __syncthreads();                     // cur buf loads done; prev reads done
    if (it + 1 < NIT) issue((it + 1) & 1, (it + 1) * BK);
    const int ab = (it & 1) * (ASEG * 512);
    const int bb = (it & 1) * (BSEG * 512);
    bf16x8 af[4], bfr[NT];
    #pragma unroll
    for (int mt = 0; mt < 4; ++mt)
      af[mt] = *(const bf16x8*)&As[ab + (wm * 4 + mt) * 512 + lq * 128 + lr * 8];
    #pragma unroll
    for (int nt = 0; nt < NT; ++nt)
      bfr[nt] = *(const bf16x8*)&Bs[bb + (wn * (BN / 32) + nt) * 512 + lq * 128 + lr * 8];
    #pragma unroll
    for (int nt = 0; nt < NT; ++nt)      // nt OUTER: srcA constant inside
      #pragma unroll
      for (int mt = 0; mt < 4; ++mt)
        acc[mt][nt] = mfma16(bfr[nt], af[mt], acc[mt][nt]);
  }

  // Epilogue (swapped layout): row = m0+wm*64+mt*16+lr ; cols = base+lq*4+{0..3}
  if (MODE == 2 && n0 >= voff) {
    // V region -> VT[(b*768 + d)][s], d = col - voff
    #pragma unroll
    for (int mt = 0; mt < 4; ++mt) {
      int row = m0 + wm * 64 + mt * 16 + lr;
      int bb2 = row >> 10, s = row & 1023;
      #pragma unroll
      for (int nt = 0; nt < NT; ++nt) {
        int col = n0 + wn * (BN / 2) + nt * 16 + lq * 4;
        ushort4v bvv = *(const ushort4v*)&bias[col];
        int dbase = bb2 * 768 + (col - voff);
        #pragma unroll
        for (int r = 0; r < 4; ++r)
          VTp[(size_t)(dbase + r) * 1024 + s] = f2b(acc[mt][nt][r] + b2f(bvv[r]));
      }
    }
  } else {
    #pragma unroll
    for (int mt = 0; mt < 4; ++mt) {
      int row = m0 + wm * 64 + mt * 16 + lr;
      #pragma unroll
      for (int nt = 0; nt < NT; ++nt) {
        int col = n0 + wn * (BN / 2) + nt * 16 + lq * 4;
        ushort4v bvv = *(const ushort4v*)&bias[col];
        ushort4v ov;
        #pragma unroll
        for (int r = 0; r < 4; ++r) {
          float v = acc[mt][nt][r] + b2f(bvv[r]);
          if (MODE == 1) v = gelu_f(v);
          ov[r] = f2b(v);
        }
        *(ushort4v*)&C[(size_t)row * N + col] = ov;
      }
    }
  }
}

// ---------- flash attention: 4 waves, 32 q-rows/wave, swapped-operand MFMA ------
// grid (bh=96, qt=8): XCD = bh%8 -> each bh's K/V L2-resident on one XCD.
// r5-structure inner loop (attn is latency-bound; low VGPR > srcA reuse — r6's
// sc[2][8] hoist cost 2x occupancy and 2x time; do not re-hoist).
__global__ __launch_bounds__(256) void attn_kernel(
    const u16* __restrict__ Q, const u16* __restrict__ Kb,
    const u16* __restrict__ VT, u16* __restrict__ CTX, int qk_stride) {
  constexpr int LDK = 72, LDV = 136, LDP = 136;
  __shared__ u16 Ks[128 * LDK];          // [s][d]
  __shared__ u16 Vs[64 * LDV];           // [d][s]
  __shared__ u16 Ps[4][16 * LDP];        // per-wave P [q][k]
  const int tid = threadIdx.x;
  const int w = tid >> 6, lane = tid & 63;
  const int lr = lane & 15, lq = lane >> 4;
  const int bh = blockIdx.x, qt = blockIdx.y;
  const int b = bh / 12, h = bh % 12;
  const size_t qrow0 = (size_t)(b * 1024 + qt * 128 + w * 32);
  bf16x8 a0[2], a1[2];
  #pragma unroll
  for (int t = 0; t < 2; ++t) {
    const u16* qp = &Q[(qrow0 + t * 16 + lr) * qk_stride + h * 64];
    a0[t] = *(const bf16x8*)&qp[lq * 8];
    a1[t] = *(const bf16x8*)&qp[32 + lq * 8];
  }
  const int kcol = h * 64;
  floatx4 o[2][4] = {};
  float lsum[2] = {0.f, 0.f};

  for (int c = 0; c < 8; ++c) {
    const int k0 = c * 128;
    __syncthreads();                     // prev chunk fully consumed
    #pragma unroll
    for (int i = 0; i < 4; ++i) {        // stage K chunk [128][64]
      int idx = i * 256 + tid;
      int row = idx >> 3, seg = idx & 7;
      *(ushort8*)&Ks[row * LDK + seg * 8] =
          *(const ushort8*)&Kb[(size_t)(b * 1024 + k0 + row) * qk_stride + kcol + seg * 8];
    }
    #pragma unroll
    for (int i = 0; i < 4; ++i) {        // stage V^T chunk [64][128]
      int idx = i * 256 + tid;
      int row = idx >> 4, seg = idx & 15;
      *(ushort8*)&Vs[row * LDV + seg * 8] =
          *(const ushort8*)&VT[((size_t)bh * 64 + row) * 1024 + k0 + seg * 8];
    }
    __syncthreads();
    u16* pw = Ps[w];
    #pragma unroll
    for (int t = 0; t < 2; ++t) {
      #pragma unroll
      for (int nb = 0; nb < 8; ++nb) {
        const u16* kp = &Ks[(nb * 16 + lr) * LDK];
        floatx4 a = {};
        a = mfma16(*(const bf16x8*)&kp[lq * 8], a0[t], a);        // SWAPPED
        a = mfma16(*(const bf16x8*)&kp[32 + lq * 8], a1[t], a);
        ushort4v pv;
        #pragma unroll
        for (int r = 0; r < 4; ++r) {
          float p = __expf(a[r] * 0.125f);
          lsum[t] += p;
          pv[r] = f2b(p);
        }
        *(ushort4v*)&pw[lr * LDP + nb * 16 + lq * 4] = pv;        // b64 write
      }
      #pragma unroll
      for (int ks = 0; ks < 4; ++ks) {
        bf16x8 af = *(const bf16x8*)&pw[lr * LDP + ks * 32 + lq * 8];
        #pragma unroll
        for (int nt = 0; nt < 4; ++nt) {
          bf16x8 bv = *(const bf16x8*)&Vs[(nt * 16 + lr) * LDV + ks * 32 + lq * 8];
          o[t][nt] = mfma16(bv, af, o[t][nt]);                    // SWAPPED
        }
      }
    }
  }
  #pragma unroll
  for (int t = 0; t < 2; ++t) {
    float v = lsum[t];
    v += __shfl_xor(v, 16);
    v += __shfl_xor(v, 32);
    lsum[t] = 1.0f / v;
  }
  #pragma unroll
  for (int t = 0; t < 2; ++t) {
    size_t row = qrow0 + t * 16 + lr;
    #pragma unroll
    for (int nt = 0; nt < 4; ++nt) {
      ushort4v ov;
      #pragma unroll
      for (int r = 0; r < 4; ++r) ov[r] = f2b(o[t][nt][r] * lsum[t]);
      *(ushort4v*)&CTX[row * 768 + h * 64 + nt * 16 + lq * 4] = ov;
    }
  }
}

// ---------- residual + LayerNorm (torch: ddof=1, eps added to std) --------------
template <int OUT_MODE>
__global__ __launch_bounds__(256) void add_ln_kernel(
    const u16* __restrict__ X, const u16* __restrict__ Y,
    const u16* __restrict__ W, const u16* __restrict__ B,
    void* __restrict__ O, const int* __restrict__ flag, int row0) {
  const int wid = threadIdx.x >> 6, lane = threadIdx.x & 63;
  const size_t lrow = (size_t)blockIdx.x * 4 + wid;
  const size_t orow = lrow + row0;
  const u16* xp = X + lrow * 768;
  const u16* yp = Y + lrow * 768;
  float v[12];
  float s = 0.f, ss = 0.f;
  #pragma unroll
  for (int i = 0; i < 3; ++i) {
    int base = (lane + 64 * i) * 4;
    ushort4v xv = *(const ushort4v*)&xp[base];
    ushort4v yv = *(const ushort4v*)&yp[base];
    #pragma unroll
    for (int j = 0; j < 4; ++j) {
      float t = b2f(xv[j]) + b2f(yv[j]);
      v[i * 4 + j] = t;
      s += t;
      ss += t * t;
    }
  }
  #pragma unroll
  for (int m = 1; m < 64; m <<= 1) {
    s += __shfl_xor(s, m);
    ss += __shfl_xor(ss, m);
  }
  float mean = s * (1.0f / 768.0f);
  float var = (ss - 768.0f * mean * mean) * (1.0f / 767.0f);
  var = fmaxf(var, 0.0f);
  float inv = 1.0f / (sqrtf(var) + 1e-6f);
  bool f32out = (OUT_MODE == 1) && (*flag != 0);
  #pragma unroll
  for (int i = 0; i < 3; ++i) {
    int base = (lane + 64 * i) * 4;
    ushort4v wv = *(const ushort4v*)&W[base];
    ushort4v bv = *(const ushort4v*)&B[base];
    floatx4 fv;
    ushort4v ov;
    #pragma unroll
    for (int j = 0; j < 4; ++j) {
      float t = (v[i * 4 + j] - mean) * inv * b2f(wv[j]) + b2f(bv[j]);
      fv[j] = t;
      ov[j] = f2b(t);
    }
    if (f32out)
      *(floatx4*)&((float*)O)[orow * 768 + base] = fv;
    else
      *(ushort4v*)&((u16*)O)[orow * 768 + base] = ov;
  }
}

// --------------------------------------------------------------------------------
extern "C" void kernel_launch(void* const* d_in, const int* in_sizes, int n_in,
                              void* d_out, int out_size, void* d_ws, size_t ws_size,
                              hipStream_t stream) {
  const void* x = d_in[0];
  char* ws = (char*)d_ws;
  const size_t ACT = (size_t)8192 * 768 * 2;     // 12,582,912
  int* flag = (int*)(ws);
  u16* BIAS = (u16*)(ws + 512);
  size_t off = 32768;
  u16* WQKVT = (u16*)(ws + off); off += (size_t)2304 * 768 * 2;   // wq|wk|wv ^T
  u16* WOT   = (u16*)(ws + off); off += (size_t)768 * 768 * 2;
  u16* W1T   = (u16*)(ws + off); off += (size_t)768 * 3072 * 2;
  u16* W2T   = (u16*)(ws + off); off += (size_t)768 * 3072 * 2;
  const size_t base = off;                        // 14,188,544

  u16* BQKV = BIAS + 0;    u16* BOc = BIAS + 2304;
  u16* B1c  = BIAS + 3072; u16* B2c = BIAS + 6144;
  u16* L1W  = BIAS + 6912; u16* L1B = BIAS + 7680;
  u16* L2W  = BIAS + 8448; u16* L2B = BIAS + 9216;

  WPtrs wp;
  wp.in[0] = d_in[2]; wp.in[1] = d_in[4]; wp.in[2] = d_in[6];
  wp.in[3] = d_in[8]; wp.in[4] = d_in[10]; wp.in[5] = d_in[12];
  BiasPtrs bp;
  bp.p[0] = d_in[3];  bp.p[1] = d_in[5];  bp.p[2] = d_in[7];  bp.p[3] = d_in[9];
  bp.p[4] = d_in[11]; bp.p[5] = d_in[13]; bp.p[6] = d_in[14]; bp.p[7] = d_in[15];
  bp.p[8] = d_in[16]; bp.p[9] = d_in[17];

  u16* XC = (u16*)(ws + base);                   // same slot in both paths

  detect_dtype<<<1, 256, 0, stream>>>((const u16*)x, flag);
  prep_all<<<13096, 256, 0, stream>>>(wp, bp, x, flag, WQKVT, WOT, W1T, W2T,
                                      BIAS, XC);

  if (ws_size >= base + 6 * ACT) {
    // ---- PATH A: full-M FFN, fused QKV (+V^T fused into epilogue) ----
    u16* Q3  = (u16*)(ws + base + ACT);      // Q|K (V cols -> VT); later ATT, FF tail
    u16* VTb = (u16*)(ws + base + 4 * ACT);  // V^T; later FFO
    u16* CTXb= (u16*)(ws + base + 5 * ACT);  // ctx; later H1
    u16* ATT = Q3;
    u16* H1  = CTXb;
    u16* FF  = XC;                           // 4*ACT contiguous = XC+Q3
    u16* FFO = VTb;

    gemm_bt<128, 2><<<dim3(64, 18), 256, 0, stream>>>(XC, WQKVT, BQKV, Q3, VTb, 2304, 768, 1536);
    attn_kernel<<<dim3(96, 8), 256, 0, stream>>>(Q3, Q3 + 768, VTb, CTXb, 2304);
    gemm_bt<64, 0><<<dim3(64, 12), 256, 0, stream>>>(CTXb, WOT, BOc, ATT, nullptr, 768, 768, 0);
    add_ln_kernel<0><<<2048, 256, 0, stream>>>(XC, ATT, L1W, L1B, H1, flag, 0);
    gemm_bt<128, 1><<<dim3(64, 24), 256, 0, stream>>>(H1, W1T, B1c, FF, nullptr, 3072, 768, 0);
    gemm_bt<64, 0><<<dim3(64, 12), 256, 0, stream>>>(FF, W2T, B2c, FFO, nullptr, 768, 3072, 0);
    add_ln_kernel<1><<<2048, 256, 0, stream>>>(H1, FFO, L2W, L2B, d_out, flag, 0);
  } else {
    // ---- PATH B: 77.1 MB layout, 2-chunk FFN ----
    u16* SA = (u16*)(ws + base + 1 * ACT);   // Q -> ATT
    u16* SB = (u16*)(ws + base + 2 * ACT);   // K -> H1
    u16* SC = (u16*)(ws + base + 3 * ACT);   // VT
    u16* SD = (u16*)(ws + base + 4 * ACT);   // CTX -> FFO chunk
    u16* WQT = WQKVT, *WKT = WQKVT + 768 * 768, *WVT = WQKVT + 2 * 768 * 768;

    gemm_bt<64, 0><<<dim3(64, 12), 256, 0, stream>>>(XC, WQT, BQKV, SA, nullptr, 768, 768, 0);
    gemm_bt<64, 0><<<dim3(64, 12), 256, 0, stream>>>(XC, WKT, BQKV + 768, SB, nullptr, 768, 768, 0);
    gemm_bt<64, 2><<<dim3(64, 12), 256, 0, stream>>>(XC, WVT, BQKV + 1536, SD, SC, 768, 768, 0);
    attn_kernel<<<dim3(96, 8), 256, 0, stream>>>(SA, SB, SC, SD, 768);
    gemm_bt<64, 0><<<dim3(64, 12), 256, 0, stream>>>(SD, WOT, BOc, SA, nullptr, 768, 768, 0);
    add_ln_kernel<0><<<2048, 256, 0, stream>>>(XC, SA, L1W, L1B, SB, flag, 0);
    for (int c = 0; c < 2; ++c) {
      const u16* h1c = SB + (size_t)c * 4096 * 768;
      u16* FFc = XC;                         // XC+SA contiguous: 25.17 MB
      gemm_bt<128, 1><<<dim3(32, 24), 256, 0, stream>>>(h1c, W1T, B1c, FFc, nullptr, 3072, 768, 0);
      gemm_bt<64, 0><<<dim3(32, 12), 256, 0, stream>>>(FFc, W2T, B2c, SD, nullptr, 768, 3072, 0);
      add_ln_kernel<1><<<1024, 256, 0, stream>>>(h1c, SD, L2W, L2B, d_out, flag, c * 4096);
    }
  }
}

// Round 9
// 388.950 us; speedup vs baseline: 1.3181x; 1.3181x over previous
//
#include <hip/hip_runtime.h>

typedef unsigned short u16;
typedef __attribute__((ext_vector_type(8))) __bf16 bf16x8;
typedef __attribute__((ext_vector_type(8))) unsigned short ushort8;
typedef __attribute__((ext_vector_type(4))) unsigned short ushort4v;
typedef __attribute__((ext_vector_type(4))) float floatx4;

__device__ __forceinline__ float b2f(u16 u) {
  union { unsigned int i; float f; } v; v.i = ((unsigned int)u) << 16; return v.f;
}
__device__ __forceinline__ u16 f2b(float f) {
  union { float f; unsigned int i; } v; v.f = f;
  unsigned int u = v.i;
  unsigned int r = (u + 0x7fffu + ((u >> 16) & 1u)) >> 16;
  return (u16)r;
}
__device__ __forceinline__ float fast_tanh(float z) {
  float e = __expf(2.0f * z);
  return 1.0f - 2.0f / (e + 1.0f);
}
__device__ __forceinline__ float gelu_f(float x) {
  float t = fast_tanh(0.7978845608028654f * (x + 0.044715f * x * x * x));
  return 0.5f * x * (1.0f + t);
}
__device__ __forceinline__ floatx4 mfma16(bf16x8 a, bf16x8 b, floatx4 c) {
  return __builtin_amdgcn_mfma_f32_16x16x32_bf16(a, b, c, 0, 0, 0);
}
#define GLL16(gp, lp)                                                        \
  __builtin_amdgcn_global_load_lds(                                          \
      (const __attribute__((address_space(1))) unsigned int*)(gp),           \
      (__attribute__((address_space(3))) unsigned int*)(lp), 16, 0, 0)

// ---------- dtype detector: fp32 inputs (flag=1) vs bf16 (flag=0) ---------------
__global__ __launch_bounds__(256) void detect_dtype(
    const u16* __restrict__ x, int* __restrict__ flag) {
  __shared__ int cnt;
  if (threadIdx.x == 0) cnt = 0;
  __syncthreads();
  int ok = 0;
  #pragma unroll
  for (int k = 0; k < 16; ++k) {
    int idx = threadIdx.x + k * 256;
    u16 u = x[2 * idx];
    int e = (u >> 7) & 0xff;
    ok += (e >= 110 && e <= 143) ? 1 : 0;
  }
  atomicAdd(&cnt, ok);
  __syncthreads();
  if (threadIdx.x == 0) *flag = (cnt < 2048) ? 1 : 0;
}

// ---------- ONE prep kernel: 6 weight transposes + bias convert + x convert -----
struct WPtrs { const void* in[6]; };
struct BiasPtrs { const void* p[10]; };
__constant__ int kBiasOffs[11] = {0, 768, 1536, 2304, 3072, 6144,
                                  6912, 7680, 8448, 9216, 9984};
__global__ __launch_bounds__(256) void prep_all(
    WPtrs wp, BiasPtrs bp, const void* __restrict__ x,
    const int* __restrict__ flag, u16* __restrict__ WQKVT,
    u16* __restrict__ WOT, u16* __restrict__ W1T, u16* __restrict__ W2T,
    u16* __restrict__ BIAS, u16* __restrict__ XC) {
  const int id = blockIdx.x;
  const int tid = threadIdx.x;
  const int fp32 = *flag;
  if (id < 6912) {                       // weight transpose tiles
    __shared__ u16 tile[32][33];
    const void* in; u16* out; int K, N, bx, by;
    if (id < 2304) {                     // wq, wk, wv, wo : 768x768
      int widx = id / 576, r = id % 576;
      in = wp.in[widx];
      out = (widx < 3) ? (WQKVT + (size_t)widx * 768 * 768) : WOT;
      K = 768; N = 768; bx = r % 24; by = r / 24;
    } else if (id < 4608) {              // w1: 768x3072
      int r = id - 2304;
      in = wp.in[4]; out = W1T; K = 768; N = 3072; bx = r % 96; by = r / 96;
    } else {                             // w2: 3072x768
      int r = id - 4608;
      in = wp.in[5]; out = W2T; K = 3072; N = 768; bx = r % 24; by = r / 24;
    }
    const int tx = tid & 31, ty = tid >> 5;
    int xi = bx * 32 + tx;
    int y0 = by * 32;
    #pragma unroll
    for (int i = ty; i < 32; i += 8) {
      size_t src = (size_t)(y0 + i) * N + xi;
      tile[i][tx] = fp32 ? f2b(((const float*)in)[src]) : ((const u16*)in)[src];
    }
    __syncthreads();
    int xo = by * 32 + tx;
    int yo0 = bx * 32;
    #pragma unroll
    for (int i = ty; i < 32; i += 8)
      out[(size_t)(yo0 + i) * K + xo] = tile[tx][i];
  } else if (id < 6952) {                // biases + LN params (9984 elems)
    int t = (id - 6912) * 256 + tid;
    if (t < 9984) {
      int seg = 0;
      #pragma unroll
      for (int s = 0; s < 10; ++s) seg += (t >= kBiasOffs[s + 1]) ? 1 : 0;
      int j = t - kBiasOffs[seg];
      float v = fp32 ? ((const float*)bp.p[seg])[j]
                     : b2f(((const u16*)bp.p[seg])[j]);
      BIAS[t] = f2b(v);
    }
  } else {                               // x convert (1,572,864 x 4-elem groups)
    int i = (id - 6952) * 256 + tid;
    ushort4v o;
    if (fp32) {
      floatx4 v = ((const floatx4*)x)[i];
      #pragma unroll
      for (int j = 0; j < 4; ++j) o[j] = f2b(v[j]);
    } else {
      o = ((const ushort4v*)x)[i];
    }
    ((ushort4v*)XC)[i] = o;
  }
}

// ---------- GEMM: BK=64 DOUBLE-BUFFERED, one barrier/iter -----------------------
// r7's exact staging/swizzle/read addressing (known-good: FFN1 70.6us) + dbuf:
//   issue(buf0); barrier; loop{ issue(next); compute(cur); barrier; }
// Same barrier count as r7 (K/64), but each vmcnt(0) drain covers loads that
// flew during a full 32-MFMA compute phase (r8 evidence: BK=32 doubled the
// barrier count and regressed; barrier_count x residual_drain is the metric).
// SWAPPED operands (C^T frags, vector stores), nt-outer (srcA reuse, r4/r5).
// Modes: 0=std, 1=gelu, 2=QKV (cols>=voff scatter-transposed to VT).
template <int BN, int MODE>
__global__ __launch_bounds__(256) void gemm_bt(
    const u16* __restrict__ A, const u16* __restrict__ Bt,
    const u16* __restrict__ bias, u16* __restrict__ C,
    u16* __restrict__ VTp, int N, int K, int voff) {
  constexpr int BM = 128, BK = 64;
  constexpr int NT = BN / 32;
  __shared__ u16 As[2 * BM * BK];       // 32 KB
  __shared__ u16 Bs[2 * BN * BK];       // 32 or 16 KB
  const int tid = threadIdx.x;
  const int lane = tid & 63, wid = tid >> 6;
  const int wm = wid & 1, wn = wid >> 1;
  const int m0 = blockIdx.x * BM, n0 = blockIdx.y * BN;
  const int lr = lane & 15, lq = lane >> 4;
  const int lrow = lane >> 3;            // row within an 8-row segment
  const int lclog = (lane & 7) ^ lrow;   // logical 8-u16 chunk (XOR swizzle)
  floatx4 acc[4][NT] = {};
  const int NIT = K / BK;

  auto issue = [&](int buf, int k0) {
    #pragma unroll
    for (int i = 0; i < 4; ++i) {        // A: 16 segs of 8 rows (1 KB each)
      int seg = wid * 4 + i;
      int row = seg * 8 + lrow;
      const u16* gp = &A[(size_t)(m0 + row) * K + k0 + lclog * 8];
      GLL16(gp, &As[buf * (BM * BK) + seg * 512]);
    }
    #pragma unroll
    for (int i = 0; i < BN / 32; ++i) {  // B: BN/8 segs
      int seg = wid * (BN / 32) + i;
      int row = seg * 8 + lrow;
      const u16* gp = &Bt[(size_t)(n0 + row) * K + k0 + lclog * 8];
      GLL16(gp, &Bs[buf * (BN * BK) + seg * 512]);
    }
  };

  issue(0, 0);
  __syncthreads();                       // drain prologue loads (once)
  for (int it = 0; it < NIT; ++it) {
    if (it + 1 < NIT) issue((it + 1) & 1, (it + 1) * BK);
    const int ab = (it & 1) * (BM * BK);
    const int bb = (it & 1) * (BN * BK);
    #pragma unroll
    for (int kk = 0; kk < 2; ++kk) {
      const int ch = ((kk * 4 + lq) ^ (lr & 7)) * 8;   // swizzled chunk offset
      bf16x8 af[4], bfr[NT];
      #pragma unroll
      for (int mt = 0; mt < 4; ++mt)
        af[mt] = *(const bf16x8*)&As[ab + (wm * 64 + mt * 16 + lr) * BK + ch];
      #pragma unroll
      for (int nt = 0; nt < NT; ++nt)
        bfr[nt] = *(const bf16x8*)&Bs[bb + (wn * (BN / 2) + nt * 16 + lr) * BK + ch];
      #pragma unroll
      for (int nt = 0; nt < NT; ++nt)    // nt OUTER: srcA constant inside
        #pragma unroll
        for (int mt = 0; mt < 4; ++mt)
          acc[mt][nt] = mfma16(bfr[nt], af[mt], acc[mt][nt]);
    }
    __syncthreads();                     // drains next-buf loads (flew thru compute)
  }

  // Epilogue (swapped layout): row = m0+wm*64+mt*16+lr ; cols = base+lq*4+{0..3}
  if (MODE == 2 && n0 >= voff) {
    // V region -> VT[(b*768 + d)][s], d = col - voff
    #pragma unroll
    for (int mt = 0; mt < 4; ++mt) {
      int row = m0 + wm * 64 + mt * 16 + lr;
      int bb2 = row >> 10, s = row & 1023;
      #pragma unroll
      for (int nt = 0; nt < NT; ++nt) {
        int col = n0 + wn * (BN / 2) + nt * 16 + lq * 4;
        ushort4v bvv = *(const ushort4v*)&bias[col];
        int dbase = bb2 * 768 + (col - voff);
        #pragma unroll
        for (int r = 0; r < 4; ++r)
          VTp[(size_t)(dbase + r) * 1024 + s] = f2b(acc[mt][nt][r] + b2f(bvv[r]));
      }
    }
  } else {
    #pragma unroll
    for (int mt = 0; mt < 4; ++mt) {
      int row = m0 + wm * 64 + mt * 16 + lr;
      #pragma unroll
      for (int nt = 0; nt < NT; ++nt) {
        int col = n0 + wn * (BN / 2) + nt * 16 + lq * 4;
        ushort4v bvv = *(const ushort4v*)&bias[col];
        ushort4v ov;
        #pragma unroll
        for (int r = 0; r < 4; ++r) {
          float v = acc[mt][nt][r] + b2f(bvv[r]);
          if (MODE == 1) v = gelu_f(v);
          ov[r] = f2b(v);
        }
        *(ushort4v*)&C[(size_t)row * N + col] = ov;
      }
    }
  }
}

// ---------- flash attention: 4 waves, 32 q-rows/wave, swapped-operand MFMA ------
// grid (bh=96, qt=8): XCD = bh%8 -> each bh's K/V L2-resident on one XCD.
// r5-structure inner loop (attn is latency-bound; low VGPR > srcA reuse — r6's
// sc[2][8] hoist cost 2x occupancy and 2x time; do not re-hoist).
__global__ __launch_bounds__(256) void attn_kernel(
    const u16* __restrict__ Q, const u16* __restrict__ Kb,
    const u16* __restrict__ VT, u16* __restrict__ CTX, int qk_stride) {
  constexpr int LDK = 72, LDV = 136, LDP = 136;
  __shared__ u16 Ks[128 * LDK];          // [s][d]
  __shared__ u16 Vs[64 * LDV];           // [d][s]
  __shared__ u16 Ps[4][16 * LDP];        // per-wave P [q][k]
  const int tid = threadIdx.x;
  const int w = tid >> 6, lane = tid & 63;
  const int lr = lane & 15, lq = lane >> 4;
  const int bh = blockIdx.x, qt = blockIdx.y;
  const int b = bh / 12, h = bh % 12;
  const size_t qrow0 = (size_t)(b * 1024 + qt * 128 + w * 32);
  bf16x8 a0[2], a1[2];
  #pragma unroll
  for (int t = 0; t < 2; ++t) {
    const u16* qp = &Q[(qrow0 + t * 16 + lr) * qk_stride + h * 64];
    a0[t] = *(const bf16x8*)&qp[lq * 8];
    a1[t] = *(const bf16x8*)&qp[32 + lq * 8];
  }
  const int kcol = h * 64;
  floatx4 o[2][4] = {};
  float lsum[2] = {0.f, 0.f};

  for (int c = 0; c < 8; ++c) {
    const int k0 = c * 128;
    __syncthreads();                     // prev chunk fully consumed
    #pragma unroll
    for (int i = 0; i < 4; ++i) {        // stage K chunk [128][64]
      int idx = i * 256 + tid;
      int row = idx >> 3, seg = idx & 7;
      *(ushort8*)&Ks[row * LDK + seg * 8] =
          *(const ushort8*)&Kb[(size_t)(b * 1024 + k0 + row) * qk_stride + kcol + seg * 8];
    }
    #pragma unroll
    for (int i = 0; i < 4; ++i) {        // stage V^T chunk [64][128]
      int idx = i * 256 + tid;
      int row = idx >> 4, seg = idx & 15;
      *(ushort8*)&Vs[row * LDV + seg * 8] =
          *(const ushort8*)&VT[((size_t)bh * 64 + row) * 1024 + k0 + seg * 8];
    }
    __syncthreads();
    u16* pw = Ps[w];
    #pragma unroll
    for (int t = 0; t < 2; ++t) {
      #pragma unroll
      for (int nb = 0; nb < 8; ++nb) {
        const u16* kp = &Ks[(nb * 16 + lr) * LDK];
        floatx4 a = {};
        a = mfma16(*(const bf16x8*)&kp[lq * 8], a0[t], a);        // SWAPPED
        a = mfma16(*(const bf16x8*)&kp[32 + lq * 8], a1[t], a);
        ushort4v pv;
        #pragma unroll
        for (int r = 0; r < 4; ++r) {
          float p = __expf(a[r] * 0.125f);
          lsum[t] += p;
          pv[r] = f2b(p);
        }
        *(ushort4v*)&pw[lr * LDP + nb * 16 + lq * 4] = pv;        // b64 write
      }
      #pragma unroll
      for (int ks = 0; ks < 4; ++ks) {
        bf16x8 af = *(const bf16x8*)&pw[lr * LDP + ks * 32 + lq * 8];
        #pragma unroll
        for (int nt = 0; nt < 4; ++nt) {
          bf16x8 bv = *(const bf16x8*)&Vs[(nt * 16 + lr) * LDV + ks * 32 + lq * 8];
          o[t][nt] = mfma16(bv, af, o[t][nt]);                    // SWAPPED
        }
      }
    }
  }
  #pragma unroll
  for (int t = 0; t < 2; ++t) {
    float v = lsum[t];
    v += __shfl_xor(v, 16);
    v += __shfl_xor(v, 32);
    lsum[t] = 1.0f / v;
  }
  #pragma unroll
  for (int t = 0; t < 2; ++t) {
    size_t row = qrow0 + t * 16 + lr;
    #pragma unroll
    for (int nt = 0; nt < 4; ++nt) {
      ushort4v ov;
      #pragma unroll
      for (int r = 0; r < 4; ++r) ov[r] = f2b(o[t][nt][r] * lsum[t]);
      *(ushort4v*)&CTX[row * 768 + h * 64 + nt * 16 + lq * 4] = ov;
    }
  }
}

// ---------- residual + LayerNorm (torch: ddof=1, eps added to std) --------------
template <int OUT_MODE>
__global__ __launch_bounds__(256) void add_ln_kernel(
    const u16* __restrict__ X, const u16* __restrict__ Y,
    const u16* __restrict__ W, const u16* __restrict__ B,
    void* __restrict__ O, const int* __restrict__ flag, int row0) {
  const int wid = threadIdx.x >> 6, lane = threadIdx.x & 63;
  const size_t lrow = (size_t)blockIdx.x * 4 + wid;
  const size_t orow = lrow + row0;
  const u16* xp = X + lrow * 768;
  const u16* yp = Y + lrow * 768;
  float v[12];
  float s = 0.f, ss = 0.f;
  #pragma unroll
  for (int i = 0; i < 3; ++i) {
    int base = (lane + 64 * i) * 4;
    ushort4v xv = *(const ushort4v*)&xp[base];
    ushort4v yv = *(const ushort4v*)&yp[base];
    #pragma unroll
    for (int j = 0; j < 4; ++j) {
      float t = b2f(xv[j]) + b2f(yv[j]);
      v[i * 4 + j] = t;
      s += t;
      ss += t * t;
    }
  }
  #pragma unroll
  for (int m = 1; m < 64; m <<= 1) {
    s += __shfl_xor(s, m);
    ss += __shfl_xor(ss, m);
  }
  float mean = s * (1.0f / 768.0f);
  float var = (ss - 768.0f * mean * mean) * (1.0f / 767.0f);
  var = fmaxf(var, 0.0f);
  float inv = 1.0f / (sqrtf(var) + 1e-6f);
  bool f32out = (OUT_MODE == 1) && (*flag != 0);
  #pragma unroll
  for (int i = 0; i < 3; ++i) {
    int base = (lane + 64 * i) * 4;
    ushort4v wv = *(const ushort4v*)&W[base];
    ushort4v bv = *(const ushort4v*)&B[base];
    floatx4 fv;
    ushort4v ov;
    #pragma unroll
    for (int j = 0; j < 4; ++j) {
      float t = (v[i * 4 + j] - mean) * inv * b2f(wv[j]) + b2f(bv[j]);
      fv[j] = t;
      ov[j] = f2b(t);
    }
    if (f32out)
      *(floatx4*)&((float*)O)[orow * 768 + base] = fv;
    else
      *(ushort4v*)&((u16*)O)[orow * 768 + base] = ov;
  }
}

// --------------------------------------------------------------------------------
extern "C" void kernel_launch(void* const* d_in, const int* in_sizes, int n_in,
                              void* d_out, int out_size, void* d_ws, size_t ws_size,
                              hipStream_t stream) {
  const void* x = d_in[0];
  char* ws = (char*)d_ws;
  const size_t ACT = (size_t)8192 * 768 * 2;     // 12,582,912
  int* flag = (int*)(ws);
  u16* BIAS = (u16*)(ws + 512);
  size_t off = 32768;
  u16* WQKVT = (u16*)(ws + off); off += (size_t)2304 * 768 * 2;   // wq|wk|wv ^T
  u16* WOT   = (u16*)(ws + off); off += (size_t)768 * 768 * 2;
  u16* W1T   = (u16*)(ws + off); off += (size_t)768 * 3072 * 2;
  u16* W2T   = (u16*)(ws + off); off += (size_t)768 * 3072 * 2;
  const size_t base = off;                        // 14,188,544

  u16* BQKV = BIAS + 0;    u16* BOc = BIAS + 2304;
  u16* B1c  = BIAS + 3072; u16* B2c = BIAS + 6144;
  u16* L1W  = BIAS + 6912; u16* L1B = BIAS + 7680;
  u16* L2W  = BIAS + 8448; u16* L2B = BIAS + 9216;

  WPtrs wp;
  wp.in[0] = d_in[2]; wp.in[1] = d_in[4]; wp.in[2] = d_in[6];
  wp.in[3] = d_in[8]; wp.in[4] = d_in[10]; wp.in[5] = d_in[12];
  BiasPtrs bp;
  bp.p[0] = d_in[3];  bp.p[1] = d_in[5];  bp.p[2] = d_in[7];  bp.p[3] = d_in[9];
  bp.p[4] = d_in[11]; bp.p[5] = d_in[13]; bp.p[6] = d_in[14]; bp.p[7] = d_in[15];
  bp.p[8] = d_in[16]; bp.p[9] = d_in[17];

  u16* XC = (u16*)(ws + base);                   // same slot in both paths

  detect_dtype<<<1, 256, 0, stream>>>((const u16*)x, flag);
  prep_all<<<13096, 256, 0, stream>>>(wp, bp, x, flag, WQKVT, WOT, W1T, W2T,
                                      BIAS, XC);

  if (ws_size >= base + 6 * ACT) {
    // ---- PATH A: full-M FFN, fused QKV (+V^T fused into epilogue) ----
    u16* Q3  = (u16*)(ws + base + ACT);      // Q|K (V cols -> VT); later ATT, FF tail
    u16* VTb = (u16*)(ws + base + 4 * ACT);  // V^T; later FFO
    u16* CTXb= (u16*)(ws + base + 5 * ACT);  // ctx; later H1
    u16* ATT = Q3;
    u16* H1  = CTXb;
    u16* FF  = XC;                           // 4*ACT contiguous = XC+Q3
    u16* FFO = VTb;

    gemm_bt<128, 2><<<dim3(64, 18), 256, 0, stream>>>(XC, WQKVT, BQKV, Q3, VTb, 2304, 768, 1536);
    attn_kernel<<<dim3(96, 8), 256, 0, stream>>>(Q3, Q3 + 768, VTb, CTXb, 2304);
    gemm_bt<64, 0><<<dim3(64, 12), 256, 0, stream>>>(CTXb, WOT, BOc, ATT, nullptr, 768, 768, 0);
    add_ln_kernel<0><<<2048, 256, 0, stream>>>(XC, ATT, L1W, L1B, H1, flag, 0);
    gemm_bt<128, 1><<<dim3(64, 24), 256, 0, stream>>>(H1, W1T, B1c, FF, nullptr, 3072, 768, 0);
    gemm_bt<64, 0><<<dim3(64, 12), 256, 0, stream>>>(FF, W2T, B2c, FFO, nullptr, 768, 3072, 0);
    add_ln_kernel<1><<<2048, 256, 0, stream>>>(H1, FFO, L2W, L2B, d_out, flag, 0);
  } else {
    // ---- PATH B: 77.1 MB layout, 2-chunk FFN ----
    u16* SA = (u16*)(ws + base + 1 * ACT);   // Q -> ATT
    u16* SB = (u16*)(ws + base + 2 * ACT);   // K -> H1
    u16* SC = (u16*)(ws + base + 3 * ACT);   // VT
    u16* SD = (u16*)(ws + base + 4 * ACT);   // CTX -> FFO chunk
    u16* WQT = WQKVT, *WKT = WQKVT + 768 * 768, *WVT = WQKVT + 2 * 768 * 768;

    gemm_bt<64, 0><<<dim3(64, 12), 256, 0, stream>>>(XC, WQT, BQKV, SA, nullptr, 768, 768, 0);
    gemm_bt<64, 0><<<dim3(64, 12), 256, 0, stream>>>(XC, WKT, BQKV + 768, SB, nullptr, 768, 768, 0);
    gemm_bt<64, 2><<<dim3(64, 12), 256, 0, stream>>>(XC, WVT, BQKV + 1536, SD, SC, 768, 768, 0);
    attn_kernel<<<dim3(96, 8), 256, 0, stream>>>(SA, SB, SC, SD, 768);
    gemm_bt<64, 0><<<dim3(64, 12), 256, 0, stream>>>(SD, WOT, BOc, SA, nullptr, 768, 768, 0);
    add_ln_kernel<0><<<2048, 256, 0, stream>>>(XC, SA, L1W, L1B, SB, flag, 0);
    for (int c = 0; c < 2; ++c) {
      const u16* h1c = SB + (size_t)c * 4096 * 768;
      u16* FFc = XC;                         // XC+SA contiguous: 25.17 MB
      gemm_bt<128, 1><<<dim3(32, 24), 256, 0, stream>>>(h1c, W1T, B1c, FFc, nullptr, 3072, 768, 0);
      gemm_bt<64, 0><<<dim3(32, 12), 256, 0, stream>>>(FFc, W2T, B2c, SD, nullptr, 768, 3072, 0);
      add_ln_kernel<1><<<1024, 256, 0, stream>>>(h1c, SD, L2W, L2B, d_out, flag, c * 4096);
    }
  }
}